// Round 3
// baseline (189.944 us; speedup 1.0000x reference)
//
#include <hip/hip_runtime.h>

// Quantum circuit simulator: 10 qubits, RY(theta_i) per wire + CNOT chain,
// then <X_i>, <Y_i>, <Z_i> per wire, on 32768 L2-normalized real states.
//
// Math used:
//  * state stays REAL (RY/CNOT real, input real)  -> Y_i == 0 exactly.
//  * CNOT chain (ctrl i -> tgt i+1, i=0..8) composes to final[x] = st[x ^ (x>>1)]
//    (binary->Gray map).  Folded into measurement:
//      X_w = 2/n2 * sum_{one per pair} st[y]*st[y ^ db],  db = 3<<(b-1) (d0=1), b=9-w
//      Z_w = 1/n2 * sum_y (1 - 2*parity(y_b..y_9)) * st[y]^2
//  * normalization deferred: divide quadratics by n2 = sum v^2.
//
// Layout: wave64 handles TWO states (lanes 0-31 / 32-63). Each lane holds 32
// amplitudes in VGPRs. Gates and X-sums are always register-local; 4 LDS
// round-trips (XOR-swizzled, b128/b64) re-localize bits between phases.
// No __syncthreads anywhere (wave-private LDS slabs).
//
// Bit-layouts (which amplitude bits live in the 5 register-index bits):
//   L0=[0,1,2,3,4] (load; gates w9..w5) -> RT1 -> L1=[0,1,5,6,7] (gates w4..w2)
//   -> RT2 -> L2=[0,1,2,8,9] (gates w1,w0; X9,X8,X7,X0; all Z)
//   -> RT3 -> L3=[0,5,6,7,8] (X3,X2,X1) -> RT4 -> L4=[0,2,3,4,5] (X6,X5,X4)

#define NQ 10
#define DIM 1024

__device__ __forceinline__ int swz(int u) {
    // bank swizzle on 16B units; bijective (upper bits XORed into bits 0-2)
    return u ^ ((u >> 3) & 7) ^ ((u >> 6) & 7);
}

template <int CTRL, int RMASK>
__device__ __forceinline__ float dpp_mov(float x) {
    // ctrl/rmask must be integer constant expressions for the builtin
    return __int_as_float(
        __builtin_amdgcn_update_dpp(0, __float_as_int(x), CTRL, RMASK, 0xF, true));
}

// 32-lane sum; result lands in lanes 31 and 63 (per half-wave). Pure VALU.
__device__ __forceinline__ float red32(float x) {
    x += dpp_mov<0x111, 0xF>(x);  // row_shr:1
    x += dpp_mov<0x112, 0xF>(x);  // row_shr:2
    x += dpp_mov<0x114, 0xF>(x);  // row_shr:4
    x += dpp_mov<0x118, 0xF>(x);  // row_shr:8  -> lane15/31/47/63 = row sums
    x += dpp_mov<0x142, 0xA>(x);  // row_bcast:15 into rows 1,3
    return x;
}

template <int MASK>
__device__ __forceinline__ void gate(float (&v)[32], float cc, float ss) {
#pragma unroll
    for (int j = 0; j < 32; ++j) {
        if ((j & MASK) == 0) {
            const float a0 = v[j], a1 = v[j | MASK];
            v[j]        = cc * a0 - ss * a1;
            v[j | MASK] = ss * a0 + cc * a1;
        }
    }
}

template <int MASK, int COND>
__device__ __forceinline__ float xsum(const float (&v)[32]) {
    float a = 0.f;
#pragma unroll
    for (int j = 0; j < 32; ++j)
        if ((j & COND) == 0) a = fmaf(v[j], v[j ^ MASK], a);
    return a;
}

__device__ __forceinline__ float f4alt(const float* a) {
    // sum_{k<16} (-1)^popcount(k) a[k]
    const float b0 = a[0] - a[1],   b1 = a[2] - a[3];
    const float b2 = a[4] - a[5],   b3 = a[6] - a[7];
    const float b4 = a[8] - a[9],   b5 = a[10] - a[11];
    const float b6 = a[12] - a[13], b7 = a[14] - a[15];
    const float c0 = b0 - b1, c1 = b2 - b3, c2 = b4 - b5, c3 = b6 - b7;
    return (c0 - c1) - (c2 - c3);
}

extern "C" __global__ void __launch_bounds__(256, 4)
qsim_kernel(const float* __restrict__ base, const float* __restrict__ prm,
            float* __restrict__ out) {
    __shared__ float lds[4][2048];  // 8KB slab per wave (2 states), 32KB total

    const int tid  = threadIdx.x;
    const int wid  = tid >> 6;
    const int lane = tid & 63;
    const int sub  = lane & 31;   // 5 lane bits within a state
    const int st   = lane >> 5;   // which of the wave's 2 states
    const int sid  = blockIdx.x * 8 + wid * 2 + st;
    float* slab = lds[wid];

    // Half-angle rotation coefficients (uniform; fast HW trig, h in [0, pi))
    float c[NQ], s[NQ];
#pragma unroll
    for (int i = 0; i < NQ; ++i) {
        const float h = 0.5f * prm[i];
        s[i] = __sinf(h);
        c[i] = __cosf(h);
    }

    // ---- Load L0: v[j] = amp[sub<<5 | j]; accumulate norm^2 ----
    float v[32];
    const float4* row = reinterpret_cast<const float4*>(base + (size_t)sid * DIM);
#pragma unroll
    for (int q = 0; q < 8; ++q) {
        const float4 t = row[(sub << 3) | q];
        v[4 * q + 0] = t.x; v[4 * q + 1] = t.y;
        v[4 * q + 2] = t.z; v[4 * q + 3] = t.w;
    }
    float n2 = 0.f;
#pragma unroll
    for (int j = 0; j < 32; ++j) n2 = fmaf(v[j], v[j], n2);

    // ---- Gates at L0: amp bits 0..4 == reg bits 0..4 (wires 9,8,7,6,5) ----
    gate<1>(v, c[9], s[9]);
    gate<2>(v, c[8], s[8]);
    gate<4>(v, c[7], s[7]);
    gate<8>(v, c[6], s[6]);
    gate<16>(v, c[5], s[5]);

    // ---- RT1: L0 -> L1=[0,1,5,6,7] ----
#pragma unroll
    for (int q = 0; q < 8; ++q) {
        const int u = (st << 8) | (sub << 3) | q;
        reinterpret_cast<float4*>(slab)[swz(u)] =
            make_float4(v[4 * q], v[4 * q + 1], v[4 * q + 2], v[4 * q + 3]);
    }
    asm volatile("s_waitcnt lgkmcnt(0)" ::: "memory");
#pragma unroll
    for (int q = 0; q < 8; ++q) {
        const int u = (st << 8) | (sub & 7) | (q << 3) | ((sub >> 3) << 6);
        const float4 t = reinterpret_cast<const float4*>(slab)[swz(u)];
        v[4 * q + 0] = t.x; v[4 * q + 1] = t.y;
        v[4 * q + 2] = t.z; v[4 * q + 3] = t.w;
    }

    // ---- Gates at L1: reg bits 2,3,4 == amp bits 5,6,7 (wires 4,3,2) ----
    gate<4>(v, c[4], s[4]);
    gate<8>(v, c[3], s[3]);
    gate<16>(v, c[2], s[2]);

    // ---- RT2: L1 -> L2=[0,1,2,8,9] ----
#pragma unroll
    for (int q = 0; q < 8; ++q) {
        const int u = (st << 8) | (sub & 7) | (q << 3) | ((sub >> 3) << 6);
        reinterpret_cast<float4*>(slab)[swz(u)] =
            make_float4(v[4 * q], v[4 * q + 1], v[4 * q + 2], v[4 * q + 3]);
    }
    asm volatile("s_waitcnt lgkmcnt(0)" ::: "memory");
#pragma unroll
    for (int t = 0; t < 8; ++t) {
        const int u = (st << 8) | (t & 1) | (sub << 1) |
                      (((t >> 1) & 1) << 6) | ((t >> 2) << 7);
        const float4 r = reinterpret_cast<const float4*>(slab)[swz(u)];
        v[4 * t + 0] = r.x; v[4 * t + 1] = r.y;
        v[4 * t + 2] = r.z; v[4 * t + 3] = r.w;
    }

    // ---- Gates at L2: reg bits 3,4 == amp bits 8,9 (wires 1,0) — ALL GATES DONE
    gate<8>(v, c[1], s[1]);
    gate<16>(v, c[0], s[0]);

    // ---- X at L2 (reg bits=[0,1,2,8,9]): wires 9,8,7,0 ----
    float xa[NQ], za[NQ];
    xa[9] = xsum<1, 1>(v);    // d0=1: flips y0
    xa[8] = xsum<3, 2>(v);    // d1=3: flips y0,y1
    xa[7] = xsum<6, 4>(v);    // d2=6: flips y1,y2
    xa[0] = xsum<24, 16>(v);  // d9: flips y8,y9 (reg bits 3,4)

    // ---- Z (all wires) at L2: parity-signed sums of squares ----
    // Pairwise A1/D1 directly from v (keeps peak VGPR pressure ~90, no sq[32])
    {
        float A1[16], D1[16];
#pragma unroll
        for (int k = 0; k < 16; ++k) {
            const float s0 = v[2 * k] * v[2 * k];
            const float s1 = v[2 * k + 1] * v[2 * k + 1];
            A1[k] = s0 + s1;
            D1[k] = s0 - s1;
        }
        const float I0 = f4alt(D1);  // signs over reg bits 0..4 (amp 0,1,2,8,9)
        const float I1 = f4alt(A1);  // signs over reg bits 1..4 (amp 1,2,8,9)
        float A2[8];
#pragma unroll
        for (int k = 0; k < 8; ++k) A2[k] = A1[2 * k] + A1[2 * k + 1];
        const float I2 = ((A2[0] - A2[1]) - (A2[2] - A2[3])) -
                         ((A2[4] - A2[5]) - (A2[6] - A2[7]));  // amp bits 2,8,9
        float A3[4];
#pragma unroll
        for (int k = 0; k < 4; ++k) A3[k] = A2[2 * k] + A2[2 * k + 1];
        const float I8 = (A3[0] - A3[1]) - (A3[2] - A3[3]);  // amp bits 8,9
        const float I9 = (A3[0] + A3[1]) - (A3[2] + A3[3]);  // amp bit 9

        // lane parity signs over amp bits 3..7 == sub bits 0..4
        const float sg0 = (__popc(sub) & 1) ? -1.f : 1.f;
        const float sg1 = (__popc(sub >> 1) & 1) ? -1.f : 1.f;
        const float sg2 = (__popc(sub >> 2) & 1) ? -1.f : 1.f;
        const float sg3 = (__popc(sub >> 3) & 1) ? -1.f : 1.f;
        const float sg4 = (__popc(sub >> 4) & 1) ? -1.f : 1.f;

        za[0] = I9;        // b=9
        za[1] = I8;        // b=8
        za[2] = sg4 * I8;  // b=7
        za[3] = sg3 * I8;  // b=6
        za[4] = sg2 * I8;  // b=5
        za[5] = sg1 * I8;  // b=4
        za[6] = sg0 * I8;  // b=3
        za[7] = sg0 * I2;  // b=2
        za[8] = sg0 * I1;  // b=1
        za[9] = sg0 * I0;  // b=0
    }

    // ---- RT3: L2 -> L3=[0,5,6,7,8] ----
#pragma unroll
    for (int t = 0; t < 8; ++t) {
        const int u = (st << 8) | (t & 1) | (sub << 1) |
                      (((t >> 1) & 1) << 6) | ((t >> 2) << 7);
        reinterpret_cast<float4*>(slab)[swz(u)] =
            make_float4(v[4 * t], v[4 * t + 1], v[4 * t + 2], v[4 * t + 3]);
    }
    asm volatile("s_waitcnt lgkmcnt(0)" ::: "memory");
#pragma unroll
    for (int p = 0; p < 16; ++p) {
        const int u  = (st << 8) | ((sub >> 1) & 7) | (p << 3) | ((sub >> 4) << 7);
        const int fi = (swz(u) << 2) | ((sub & 1) << 1);
        const float2 r = *reinterpret_cast<const float2*>(slab + fi);
        v[2 * p] = r.x; v[2 * p + 1] = r.y;
    }

    // ---- X at L3 (reg bits=[0,5,6,7,8]): wires 3,2,1 ----
    xa[3] = xsum<6, 4>(v);    // d6: flips y5,y6
    xa[2] = xsum<12, 8>(v);   // d7: flips y6,y7
    xa[1] = xsum<24, 16>(v);  // d8: flips y7,y8

    // ---- RT4: L3 -> L4=[0,2,3,4,5] ----
#pragma unroll
    for (int p = 0; p < 16; ++p) {
        const int u  = (st << 8) | ((sub >> 1) & 7) | (p << 3) | ((sub >> 4) << 7);
        const int fi = (swz(u) << 2) | ((sub & 1) << 1);
        *reinterpret_cast<float2*>(slab + fi) = make_float2(v[2 * p], v[2 * p + 1]);
    }
    asm volatile("s_waitcnt lgkmcnt(0)" ::: "memory");
#pragma unroll
    for (int p = 0; p < 16; ++p) {
        const int u  = (st << 8) | p | ((sub >> 1) << 4);
        const int fi = (swz(u) << 2) | ((sub & 1) << 1);
        const float2 r = *reinterpret_cast<const float2*>(slab + fi);
        v[2 * p] = r.x; v[2 * p + 1] = r.y;
    }

    // ---- X at L4 (reg bits=[0,2,3,4,5]): wires 6,5,4 ----
    xa[6] = xsum<6, 4>(v);    // d3: flips y2,y3
    xa[5] = xsum<12, 8>(v);   // d4: flips y3,y4
    xa[4] = xsum<24, 16>(v);  // d5: flips y4,y5

    // ---- Reduce over the 32 lanes of each state (DPP, pure VALU) ----
    n2 = red32(n2);
#pragma unroll
    for (int w = 0; w < NQ; ++w) {
        xa[w] = red32(xa[w]);
        za[w] = red32(za[w]);
    }

    if (sub == 31) {  // lanes 31 and 63 hold their state's totals
        const float inv = 1.0f / n2;
        float* o = out + (size_t)sid * (3 * NQ);
#pragma unroll
        for (int w = 0; w < NQ; ++w) {
            o[3 * w + 0] = 2.0f * xa[w] * inv;
            o[3 * w + 1] = 0.0f;  // state is real -> <Y> == 0 exactly
            o[3 * w + 2] = za[w] * inv;
        }
    }
}

extern "C" void kernel_launch(void* const* d_in, const int* in_sizes, int n_in,
                              void* d_out, int out_size, void* d_ws, size_t ws_size,
                              hipStream_t stream) {
    const float* base = (const float*)d_in[0];
    const float* prm  = (const float*)d_in[1];
    float* out        = (float*)d_out;
    const int nstates = in_sizes[0] / DIM;       // 32768
    const int blocks  = nstates / 8;             // 8 states per 256-thread block
    qsim_kernel<<<dim3(blocks), dim3(256), 0, stream>>>(base, prm, out);
}